// Round 1
// baseline (379.137 us; speedup 1.0000x reference)
//
#include <hip/hip_runtime.h>
#include <math.h>

// Problem constants (fixed by setup_inputs)
#define QTOT   8192
#define CDIM   256
#define LNUM   4
#define PNUM   4
#define NHEAD  8
#define DHEAD  32
#define HMAX   128
#define NV_PER_B 21760           // 128^2 + 64^2 + 32^2 + 16^2
#define MROWS  (2 * NV_PER_B)    // 43520 valid value rows
#define QPERB  4096              // batch_offsets = [0, 4096]

// ---------------------------------------------------------------------------
// Tiled NT f32 GEMM: Out[M][ldo(cols n0..)] = A[M][256] * B[N][256]^T + bias
// GATHER=1: A rows are the compact valid-value rows gathered from the
//           [B,HMAX,HMAX,L,C] values tensor.
// B rows n < nsplit come from B1, else B2 (row n-nsplit); same for bias.
// Tile 64x64, BK=16, 256 threads, 4x4 micro-tile.
// ---------------------------------------------------------------------------
template<int GATHER>
__global__ __launch_bounds__(256)
void gemm_nt(const float* __restrict__ A,
             const float* __restrict__ B1,
             const float* __restrict__ B2,
             const float* __restrict__ bias1,
             const float* __restrict__ bias2,
             float* __restrict__ Out,
             int nsplit, int ldo)
{
    __shared__ __align__(16) float As[16][68];
    __shared__ __align__(16) float Bs[16][68];
    __shared__ int rowBase[64];

    const int tid = threadIdx.x;
    const int m0 = blockIdx.x * 64;
    const int n0 = blockIdx.y * 64;

    if (GATHER) {
        if (tid < 64) {
            int r = m0 + tid;                      // compact row id < MROWS
            int b = (r >= NV_PER_B) ? 1 : 0;
            int rp = r - b * NV_PER_B;
            int l, y, x;
            if (rp < 16384)      { l = 0; y = rp >> 7; x = rp & 127; }
            else if (rp < 20480) { int rr = rp - 16384; l = 1; y = rr >> 6; x = rr & 63; }
            else if (rp < 21504) { int rr = rp - 20480; l = 2; y = rr >> 5; x = rr & 31; }
            else                 { int rr = rp - 21504; l = 3; y = rr >> 4; x = rr & 15; }
            // values element (b,y,x,l,0) flat offset
            rowBase[tid] = (((((b << 7) | y) << 7) | x) * 4 + l) << 8;
        }
        __syncthreads();
    }

    const int lrow = tid >> 2;      // 0..63 : tile row (A) / tile col (B)
    const int kseg = tid & 3;       // which float4 of the 16-wide k-slab
    const float* Arow = GATHER ? A : (A + (size_t)(m0 + lrow) * 256);
    const int bn = n0 + lrow;
    const float* Brow = (bn < nsplit) ? (B1 + (size_t)bn * 256)
                                      : (B2 + (size_t)(bn - nsplit) * 256);
    const int ty = tid >> 4;        // 0..15
    const int tx = tid & 15;        // 0..15

    float acc[4][4] = {};

    for (int kt = 0; kt < 16; ++kt) {
        const int k0 = kt * 16 + kseg * 4;
        float4 av, bv;
        if (GATHER) av = *(const float4*)(A + rowBase[lrow] + k0);
        else        av = *(const float4*)(Arow + k0);
        bv = *(const float4*)(Brow + k0);
        __syncthreads();            // previous tile's compute done
        As[kseg*4+0][lrow] = av.x; As[kseg*4+1][lrow] = av.y;
        As[kseg*4+2][lrow] = av.z; As[kseg*4+3][lrow] = av.w;
        Bs[kseg*4+0][lrow] = bv.x; Bs[kseg*4+1][lrow] = bv.y;
        Bs[kseg*4+2][lrow] = bv.z; Bs[kseg*4+3][lrow] = bv.w;
        __syncthreads();
        #pragma unroll
        for (int kk = 0; kk < 16; ++kk) {
            float4 a4 = *(const float4*)&As[kk][ty * 4];
            float4 b4 = *(const float4*)&Bs[kk][tx * 4];
            float ar[4] = {a4.x, a4.y, a4.z, a4.w};
            float br[4] = {b4.x, b4.y, b4.z, b4.w};
            #pragma unroll
            for (int i = 0; i < 4; ++i)
                #pragma unroll
                for (int j = 0; j < 4; ++j)
                    acc[i][j] = fmaf(ar[i], br[j], acc[i][j]);
        }
    }

    #pragma unroll
    for (int i = 0; i < 4; ++i) {
        const int row = m0 + ty * 4 + i;
        #pragma unroll
        for (int j = 0; j < 4; ++j) {
            const int col = n0 + tx * 4 + j;
            const float b = (col < nsplit) ? bias1[col] : bias2[col - nsplit];
            acc[i][j] += b;
        }
        float4 o = {acc[i][0], acc[i][1], acc[i][2], acc[i][3]};
        *(float4*)(Out + (size_t)row * ldo + n0 + tx * 4) = o;
    }
}

// ---------------------------------------------------------------------------
// Sampling: one block per query. 256 threads.
// Phase 1 (tid<128): per (l,p,h) combo compute sampling loc, 4 corner compact
//   rows + bilinear weights (0 if invalid) into LDS; stash attention logits.
// Phase 2 (tid<128): softmax over the 16 (l,p) logits per head.
// Phase 3 (all 256 = h*32+d): gather-accumulate into mid[q][h*32+d].
// ---------------------------------------------------------------------------
__global__ __launch_bounds__(256)
void sample_kernel(const float* __restrict__ vproj,   // [MROWS][256]
                   const float* __restrict__ qbuf,    // [Q][384]: 256 offs | 128 aw logits
                   const float* __restrict__ ref,     // [Q][2]
                   float* __restrict__ mid)           // [Q][256]
{
    __shared__ float s_logit[16][8];
    __shared__ float s_aw[16][8];
    __shared__ int   s_row[128][4];
    __shared__ float s_w[128][4];

    const int q = blockIdx.x;
    const int tid = threadIdx.x;
    const int b = (q >= QPERB) ? 1 : 0;

    if (tid < 128) {
        const int c  = tid;            // (l*4+p)*8 + h
        const int lp = c >> 3;
        const int l  = lp >> 2;
        const float offx = qbuf[(size_t)q * 384 + c * 2 + 0];
        const float offy = qbuf[(size_t)q * 384 + c * 2 + 1];
        float rx = ref[q * 2 + 0], ry = ref[q * 2 + 1];
        rx = fminf(fmaxf(rx, 0.f), 1.f);
        ry = fminf(fmaxf(ry, 0.f), 1.f);
        const float eps = 1e-5f;
        const float isx = logf(fmaxf(rx, eps) / fmaxf(1.f - rx, eps));
        const float isy = logf(fmaxf(ry, eps) / fmaxf(1.f - ry, eps));
        const float locx = 1.f / (1.f + expf(-(isx + offx)));
        const float locy = 1.f / (1.f + expf(-(isy + offy)));
        const int Wl = HMAX >> l, Hl = HMAX >> l;
        const float x = locx * (float)Wl - 0.5f;
        const float y = locy * (float)Hl - 0.5f;
        const float x0f = floorf(x), y0f = floorf(y);
        const float wx1 = x - x0f, wx0 = 1.f - wx1;
        const float wy1 = y - y0f, wy0 = 1.f - wy1;
        const int x0 = (int)x0f, y0 = (int)y0f;
        const int lo = (l == 0) ? 0 : (l == 1) ? 16384 : (l == 2) ? 20480 : 21504;
        const int base = b * NV_PER_B + lo;
        const int   xs[2] = {x0, x0 + 1};
        const int   ys[2] = {y0, y0 + 1};
        const float wxs[2] = {wx0, wx1};
        const float wys[2] = {wy0, wy1};
        #pragma unroll
        for (int cy = 0; cy < 2; ++cy)
            #pragma unroll
            for (int cx = 0; cx < 2; ++cx) {
                const int xi = xs[cx], yi = ys[cy];
                const bool valid = (xi >= 0) & (xi < Wl) & (yi >= 0) & (yi < Hl);
                const int idx = cy * 2 + cx;
                s_row[c][idx] = valid ? (base + yi * Wl + xi) : 0;
                s_w[c][idx]   = valid ? (wys[cy] * wxs[cx]) : 0.f;
            }
        s_logit[lp][c & 7] = qbuf[(size_t)q * 384 + 256 + c];
    }
    __syncthreads();
    if (tid < 128) {
        const int lp = tid >> 3, h = tid & 7;
        float m = -INFINITY;
        #pragma unroll
        for (int j = 0; j < 16; ++j) m = fmaxf(m, s_logit[j][h]);
        float s = 0.f;
        #pragma unroll
        for (int j = 0; j < 16; ++j) s += expf(s_logit[j][h] - m);
        s_aw[lp][h] = expf(s_logit[lp][h] - m) / s;
    }
    __syncthreads();

    const int h = tid >> 5;
    const int d = tid & 31;
    const int ch = h * DHEAD + d;   // == tid
    float acc = 0.f;
    #pragma unroll
    for (int lp = 0; lp < 16; ++lp) {
        const int c = lp * 8 + h;
        const float aw = s_aw[lp][h];
        float sum = 0.f;
        #pragma unroll
        for (int j = 0; j < 4; ++j)
            sum = fmaf(s_w[c][j], vproj[(size_t)s_row[c][j] * 256 + ch], sum);
        acc = fmaf(aw, sum, acc);
    }
    mid[(size_t)q * 256 + ch] = acc;
}

// ---------------------------------------------------------------------------
extern "C" void kernel_launch(void* const* d_in, const int* in_sizes, int n_in,
                              void* d_out, int out_size, void* d_ws, size_t ws_size,
                              hipStream_t stream)
{
    const float* query  = (const float*)d_in[0];
    const float* ref    = (const float*)d_in[1];
    const float* values = (const float*)d_in[2];
    const float* W_so   = (const float*)d_in[3];
    const float* b_so   = (const float*)d_in[4];
    const float* W_aw   = (const float*)d_in[5];
    const float* b_aw   = (const float*)d_in[6];
    const float* W_v    = (const float*)d_in[7];
    const float* b_v    = (const float*)d_in[8];
    const float* W_o    = (const float*)d_in[9];
    const float* b_o    = (const float*)d_in[10];
    float* out = (float*)d_out;

    float* vproj = (float*)d_ws;                       // [43520][256]
    float* qbuf  = vproj + (size_t)MROWS * 256;        // [8192][384]
    float* mid   = qbuf + (size_t)QTOT * 384;          // [8192][256]

    dim3 blk(256);
    // 1) compact value projection: v = values_valid @ W_v^T + b_v
    gemm_nt<1><<<dim3(MROWS / 64, 256 / 64), blk, 0, stream>>>(
        values, W_v, W_v, b_v, b_v, vproj, 256, 256);
    // 2) query projections: [offs | aw logits] = query @ [W_so;W_aw]^T + bias
    gemm_nt<0><<<dim3(QTOT / 64, 384 / 64), blk, 0, stream>>>(
        query, W_so, W_aw, b_so, b_aw, qbuf, 256, 384);
    // 3) deformable sampling + softmax-weighted head accumulation
    sample_kernel<<<dim3(QTOT), blk, 0, stream>>>(vproj, qbuf, ref, mid);
    // 4) output projection
    gemm_nt<0><<<dim3(QTOT / 64, 256 / 64), blk, 0, stream>>>(
        mid, W_o, W_o, b_o, b_o, out, 256, 256);
}

// Round 5
// 296.029 us; speedup vs baseline: 1.2807x; 1.2807x over previous
//
#include <hip/hip_runtime.h>
#include <math.h>

// Problem constants (fixed by setup_inputs)
#define QTOT   8192
#define LNUM   4
#define PNUM   4
#define NHEAD  8
#define DHEAD  32
#define HMAX   128
#define NV_PER_B 21760           // 128^2 + 64^2 + 32^2 + 16^2
#define MROWS  (2 * NV_PER_B)    // 43520 valid value rows
#define QPERB  4096              // batch_offsets = [0, 4096]

typedef __attribute__((ext_vector_type(8))) short bf16x8;
typedef __attribute__((ext_vector_type(4))) float f32x4;

static __device__ __forceinline__ ushort bf16_hi(float f) {
    return (ushort)(__builtin_bit_cast(unsigned int, f) >> 16);
}
static __device__ __forceinline__ ushort bf16_lo(float f, ushort hi) {
    float hf = __builtin_bit_cast(float, ((unsigned int)hi) << 16);
    return (ushort)(__builtin_bit_cast(unsigned int, f - hf) >> 16);
}

// ---------------------------------------------------------------------------
// Split-bf16 MFMA NT GEMM: Out[M][ldo] = A[M][256] * B[N][256]^T + bias
// a*b ~= ahi*bhi + ahi*blo + alo*bhi  (f32-level accuracy on bf16 MFMA pipe)
// BMxBN=128 tile, BK=32, 256 threads = 4 waves (2x2), 16x16x32 MFMA.
// Double-buffered LDS, XOR chunk-swizzle (conflict-light b128 reads).
// GATHER=1: A rows gathered from sparse [B,HMAX,HMAX,L,C] values tensor.
// B row n: n<nsplit -> B1[n], else B2[n-nsplit]; same for bias.
// ---------------------------------------------------------------------------
template<int GATHER, int BM>
__global__ __launch_bounds__(256)
void gemm_split(const float* __restrict__ A,
                const float* __restrict__ B1,
                const float* __restrict__ B2,
                const float* __restrict__ bias1,
                const float* __restrict__ bias2,
                float* __restrict__ Out,
                int nsplit, int ldo)
{
    constexpr int MI  = BM / 32;          // m-frags per wave
    constexpr int AIT = BM * 8 / 256;     // float4 staging slots per thread (A)
    __shared__ ushort sA[2][2][BM * 32];  // [buf][hi/lo][row*32 + swizzled chunk]
    __shared__ ushort sB[2][2][128 * 32];
    __shared__ int rowBase[BM];

    const int tid = threadIdx.x;
    const int m0 = blockIdx.x * BM;
    const int n0 = blockIdx.y * 128;

    if (GATHER) {
        for (int s = tid; s < BM; s += 256) {
            int r = m0 + s;
            int b = (r >= NV_PER_B) ? 1 : 0;
            int rp = r - b * NV_PER_B;
            int l, y, x;
            if (rp < 16384)      { l = 0; y = rp >> 7; x = rp & 127; }
            else if (rp < 20480) { int rr = rp - 16384; l = 1; y = rr >> 6; x = rr & 63; }
            else if (rp < 21504) { int rr = rp - 20480; l = 2; y = rr >> 5; x = rr & 31; }
            else                 { int rr = rp - 21504; l = 3; y = rr >> 4; x = rr & 15; }
            rowBase[s] = (((((b << 7) | y) << 7) | x) * 4 + l) << 8;
        }
        __syncthreads();
    }

    float4 pa[AIT], pb[4];

    // ---- global load of K-tile kt into regs ----
    auto loadA = [&](int kt) {
        #pragma unroll
        for (int i = 0; i < AIT; ++i) {
            int s = tid + i * 256;
            int r = s >> 3, c4 = s & 7;
            const float* src = GATHER
                ? A + rowBase[r] + kt * 32 + c4 * 4
                : A + (size_t)(m0 + r) * 256 + kt * 32 + c4 * 4;
            pa[i] = *(const float4*)src;
        }
        #pragma unroll
        for (int i = 0; i < 4; ++i) {
            int s = tid + i * 256;
            int r = s >> 3, c4 = s & 7;
            int bn = n0 + r;
            const float* src = ((bn < nsplit) ? B1 + (size_t)bn * 256
                                              : B2 + (size_t)(bn - nsplit) * 256)
                               + kt * 32 + c4 * 4;
            pb[i] = *(const float4*)src;
        }
    };

    // ---- convert + swizzled LDS write ----
    auto writeLDS = [&](int buf) {
        #pragma unroll
        for (int i = 0; i < AIT; ++i) {
            int s = tid + i * 256;
            int r = s >> 3, c4 = s & 7;
            float4 v = pa[i];
            ushort4 hi, lo;
            hi.x = bf16_hi(v.x); lo.x = bf16_lo(v.x, hi.x);
            hi.y = bf16_hi(v.y); lo.y = bf16_lo(v.y, hi.y);
            hi.z = bf16_hi(v.z); lo.z = bf16_lo(v.z, hi.z);
            hi.w = bf16_hi(v.w); lo.w = bf16_lo(v.w, hi.w);
            int idx = r * 32 + ((((c4 >> 1) ^ (r & 3)) << 3) | ((c4 & 1) << 2));
            *(ushort4*)&sA[buf][0][idx] = hi;
            *(ushort4*)&sA[buf][1][idx] = lo;
        }
        #pragma unroll
        for (int i = 0; i < 4; ++i) {
            int s = tid + i * 256;
            int r = s >> 3, c4 = s & 7;
            float4 v = pb[i];
            ushort4 hi, lo;
            hi.x = bf16_hi(v.x); lo.x = bf16_lo(v.x, hi.x);
            hi.y = bf16_hi(v.y); lo.y = bf16_lo(v.y, hi.y);
            hi.z = bf16_hi(v.z); lo.z = bf16_lo(v.z, hi.z);
            hi.w = bf16_hi(v.w); lo.w = bf16_lo(v.w, hi.w);
            int idx = r * 32 + ((((c4 >> 1) ^ (r & 3)) << 3) | ((c4 & 1) << 2));
            *(ushort4*)&sB[buf][0][idx] = hi;
            *(ushort4*)&sB[buf][1][idx] = lo;
        }
    };

    const int lane = tid & 63;
    const int wid  = tid >> 6;
    const int wrow = (wid >> 1) * (BM / 2);
    const int wcol = (wid & 1) * 64;
    const int fr   = lane & 15;
    const int ks   = lane >> 4;

    f32x4 acc[MI][4] = {};

    loadA(0);
    writeLDS(0);

    for (int kt = 0; kt < 8; ++kt) {
        __syncthreads();
        if (kt < 7) loadA(kt + 1);

        const int buf = kt & 1;
        bf16x8 ah[MI], al[MI], bh[4], bl[4];
        #pragma unroll
        for (int mi = 0; mi < MI; ++mi) {
            int row = wrow + mi * 16 + fr;
            int idx = row * 32 + ((ks ^ (row & 3)) << 3);
            ah[mi] = *(const bf16x8*)&sA[buf][0][idx];
            al[mi] = *(const bf16x8*)&sA[buf][1][idx];
        }
        #pragma unroll
        for (int ni = 0; ni < 4; ++ni) {
            int row = wcol + ni * 16 + fr;
            int idx = row * 32 + ((ks ^ (row & 3)) << 3);
            bh[ni] = *(const bf16x8*)&sB[buf][0][idx];
            bl[ni] = *(const bf16x8*)&sB[buf][1][idx];
        }
        #pragma unroll
        for (int mi = 0; mi < MI; ++mi)
            #pragma unroll
            for (int ni = 0; ni < 4; ++ni) {
                acc[mi][ni] = __builtin_amdgcn_mfma_f32_16x16x32_bf16(ah[mi], bh[ni], acc[mi][ni], 0, 0, 0);
                acc[mi][ni] = __builtin_amdgcn_mfma_f32_16x16x32_bf16(ah[mi], bl[ni], acc[mi][ni], 0, 0, 0);
                acc[mi][ni] = __builtin_amdgcn_mfma_f32_16x16x32_bf16(al[mi], bh[ni], acc[mi][ni], 0, 0, 0);
            }

        if (kt < 7) writeLDS((kt + 1) & 1);
    }

    // epilogue: D[row=(lane>>4)*4+r][col=lane&15] per 16x16 frag
    #pragma unroll
    for (int mi = 0; mi < MI; ++mi)
        #pragma unroll
        for (int ni = 0; ni < 4; ++ni) {
            int col = n0 + wcol + ni * 16 + fr;
            float bs = (col < nsplit) ? bias1[col] : bias2[col - nsplit];
            int rbase = m0 + wrow + mi * 16 + ks * 4;
            #pragma unroll
            for (int r = 0; r < 4; ++r)
                Out[(size_t)(rbase + r) * ldo + col] = acc[mi][ni][r] + bs;
        }
}

// ---------------------------------------------------------------------------
// Sampling: 4 queries per block, 256 threads, float4 gathers.
// ---------------------------------------------------------------------------
__global__ __launch_bounds__(256)
void sample4(const float* __restrict__ vproj,   // [MROWS][256]
             const float* __restrict__ qbuf,    // [Q][384]: 256 offs | 128 aw logits
             const float* __restrict__ ref,     // [Q][2]
             float* __restrict__ mid)           // [Q][256]
{
    __shared__ int   s_row[4][128][4];
    __shared__ float s_w[4][128][4];
    __shared__ float s_logit[4][16][8];
    __shared__ float s_aw[4][16][8];

    const int tid = threadIdx.x;
    const int q0 = blockIdx.x * 4;

    #pragma unroll
    for (int it = 0; it < 2; ++it) {
        const int cc = tid + it * 256;
        const int qq = cc >> 7, c = cc & 127;
        const int q = q0 + qq;
        const int b = (q >= QPERB) ? 1 : 0;
        const int lp = c >> 3, l = lp >> 2;
        const float offx = qbuf[(size_t)q * 384 + c * 2 + 0];
        const float offy = qbuf[(size_t)q * 384 + c * 2 + 1];
        float rx = fminf(fmaxf(ref[q * 2 + 0], 0.f), 1.f);
        float ry = fminf(fmaxf(ref[q * 2 + 1], 0.f), 1.f);
        const float eps = 1e-5f;
        const float isx = logf(fmaxf(rx, eps) / fmaxf(1.f - rx, eps));
        const float isy = logf(fmaxf(ry, eps) / fmaxf(1.f - ry, eps));
        const float locx = 1.f / (1.f + expf(-(isx + offx)));
        const float locy = 1.f / (1.f + expf(-(isy + offy)));
        const int Wl = HMAX >> l, Hl = HMAX >> l;
        const float x = locx * (float)Wl - 0.5f;
        const float y = locy * (float)Hl - 0.5f;
        const float x0f = floorf(x), y0f = floorf(y);
        const float wx1 = x - x0f, wx0 = 1.f - wx1;
        const float wy1 = y - y0f, wy0 = 1.f - wy1;
        const int x0 = (int)x0f, y0 = (int)y0f;
        const int lo = (l == 0) ? 0 : (l == 1) ? 16384 : (l == 2) ? 20480 : 21504;
        const int base = b * NV_PER_B + lo;
        const int   xs[2] = {x0, x0 + 1};
        const int   ys[2] = {y0, y0 + 1};
        const float wxs[2] = {wx0, wx1};
        const float wys[2] = {wy0, wy1};
        #pragma unroll
        for (int cy = 0; cy < 2; ++cy)
            #pragma unroll
            for (int cx = 0; cx < 2; ++cx) {
                const int xi = xs[cx], yi = ys[cy];
                const bool valid = (xi >= 0) & (xi < Wl) & (yi >= 0) & (yi < Hl);
                const int idx = cy * 2 + cx;
                s_row[qq][c][idx] = valid ? (base + yi * Wl + xi) : 0;
                s_w[qq][c][idx]   = valid ? (wys[cy] * wxs[cx]) : 0.f;
            }
        s_logit[qq][lp][c & 7] = qbuf[(size_t)q * 384 + 256 + c];
    }
    __syncthreads();

    if (tid < 32) {
        const int qq = tid >> 3, h = tid & 7;
        float m = -INFINITY;
        #pragma unroll
        for (int j = 0; j < 16; ++j) m = fmaxf(m, s_logit[qq][j][h]);
        float s = 0.f;
        #pragma unroll
        for (int j = 0; j < 16; ++j) s += expf(s_logit[qq][j][h] - m);
        const float inv = 1.f / s;
        #pragma unroll
        for (int j = 0; j < 16; ++j)
            s_aw[qq][j][h] = expf(s_logit[qq][j][h] - m) * inv;
    }
    __syncthreads();

    const int qq = tid >> 6, t6 = tid & 63;
    const int h = t6 >> 3, d4 = t6 & 7;
    const int q = q0 + qq;
    float ax = 0.f, ay = 0.f, az = 0.f, aw_ = 0.f;
    #pragma unroll
    for (int lp = 0; lp < 16; ++lp) {
        const int c = lp * 8 + h;
        const float aw = s_aw[qq][lp][h];
        float sx = 0.f, sy = 0.f, sz = 0.f, sw = 0.f;
        #pragma unroll
        for (int j = 0; j < 4; ++j) {
            const int row = s_row[qq][c][j];
            const float w = s_w[qq][c][j];
            const float4 v = *(const float4*)&vproj[(size_t)row * 256 + h * 32 + d4 * 4];
            sx = fmaf(w, v.x, sx); sy = fmaf(w, v.y, sy);
            sz = fmaf(w, v.z, sz); sw = fmaf(w, v.w, sw);
        }
        ax = fmaf(aw, sx, ax); ay = fmaf(aw, sy, ay);
        az = fmaf(aw, sz, az); aw_ = fmaf(aw, sw, aw_);
    }
    float4 o = {ax, ay, az, aw_};
    *(float4*)&mid[(size_t)q * 256 + t6 * 4] = o;
}

// ---------------------------------------------------------------------------
extern "C" void kernel_launch(void* const* d_in, const int* in_sizes, int n_in,
                              void* d_out, int out_size, void* d_ws, size_t ws_size,
                              hipStream_t stream)
{
    const float* query  = (const float*)d_in[0];
    const float* ref    = (const float*)d_in[1];
    const float* values = (const float*)d_in[2];
    const float* W_so   = (const float*)d_in[3];
    const float* b_so   = (const float*)d_in[4];
    const float* W_aw   = (const float*)d_in[5];
    const float* b_aw   = (const float*)d_in[6];
    const float* W_v    = (const float*)d_in[7];
    const float* b_v    = (const float*)d_in[8];
    const float* W_o    = (const float*)d_in[9];
    const float* b_o    = (const float*)d_in[10];
    float* out = (float*)d_out;

    float* vproj = (float*)d_ws;                       // [43520][256] f32
    float* qbuf  = vproj + (size_t)MROWS * 256;        // [8192][384]
    float* mid   = qbuf + (size_t)QTOT * 384;          // [8192][256]

    dim3 blk(256);
    // 1) compact value projection: vproj = values_valid @ W_v^T + b_v
    gemm_split<1, 128><<<dim3(MROWS / 128, 2), blk, 0, stream>>>(
        values, W_v, W_v, b_v, b_v, vproj, 256, 256);
    // 2) query projections: [offs | aw logits] = query @ [W_so;W_aw]^T + bias
    gemm_split<0, 64><<<dim3(QTOT / 64, 3), blk, 0, stream>>>(
        query, W_so, W_aw, b_so, b_aw, qbuf, 256, 384);
    // 3) deformable sampling + softmax-weighted head accumulation
    sample4<<<dim3(QTOT / 4), blk, 0, stream>>>(vproj, qbuf, ref, mid);
    // 4) output projection
    gemm_split<0, 64><<<dim3(QTOT / 64, 2), blk, 0, stream>>>(
        mid, W_o, W_o, b_o, b_o, out, 256, 256);
}

// Round 6
// 272.230 us; speedup vs baseline: 1.3927x; 1.0874x over previous
//
#include <hip/hip_runtime.h>
#include <math.h>

// Problem constants (fixed by setup_inputs)
#define QTOT   8192
#define LNUM   4
#define PNUM   4
#define NHEAD  8
#define DHEAD  32
#define HMAX   128
#define NV_PER_B 21760           // 128^2 + 64^2 + 32^2 + 16^2
#define MROWS  (2 * NV_PER_B)    // 43520 valid value rows
#define QPERB  4096              // batch_offsets = [0, 4096]

typedef __attribute__((ext_vector_type(8))) short bf16x8;
typedef __attribute__((ext_vector_type(4))) float f32x4;

static __device__ __forceinline__ ushort bf16_hi(float f) {
    return (ushort)(__builtin_bit_cast(unsigned int, f) >> 16);
}
static __device__ __forceinline__ ushort bf16_lo(float f, ushort hi) {
    float hf = __builtin_bit_cast(float, ((unsigned int)hi) << 16);
    return (ushort)(__builtin_bit_cast(unsigned int, f - hf) >> 16);
}
static __device__ __forceinline__ ushort bf16_rne(float f) {
    unsigned u = __builtin_bit_cast(unsigned int, f);
    unsigned rr = (u + 0x7FFFu + ((u >> 16) & 1u)) >> 16;
    return (ushort)rr;
}

// ---------------------------------------------------------------------------
// Split-bf16 MFMA NT GEMM: Out[M][ldo] = A[M][256] * B[N][256]^T + bias
// NPROD=3: a*b ~= ahi*bhi + ahi*blo + alo*bhi (f32-level accuracy)
// NPROD=1: plain bf16 (hi planes only, 1 MFMA) — for error-tolerant GEMMs.
// OUTBF16: store output as bf16 (RNE) instead of f32.
// BMx128 tile, BK=32, 256 threads = 4 waves (2x2), 16x16x32 MFMA.
// Double-buffered LDS, XOR chunk-swizzle (conflict-light b128 reads).
// GATHER=1: A rows gathered from sparse [B,HMAX,HMAX,L,C] values tensor.
// B row n: n<nsplit -> B1[n], else B2[n-nsplit]; same for bias.
// ---------------------------------------------------------------------------
template<int GATHER, int BM, int NPROD, int OUTBF16>
__global__ __launch_bounds__(256)
void gemm_split(const float* __restrict__ A,
                const float* __restrict__ B1,
                const float* __restrict__ B2,
                const float* __restrict__ bias1,
                const float* __restrict__ bias2,
                void* __restrict__ Out,
                int nsplit, int ldo)
{
    constexpr int MI  = BM / 32;          // m-frags per wave
    constexpr int AIT = BM * 8 / 256;     // float4 staging slots per thread (A)
    constexpr int PL  = (NPROD > 1) ? 2 : 1;   // LDS planes (hi[,lo])
    __shared__ ushort sA[2][PL][BM * 32];  // [buf][plane][row*32 + swizzled chunk]
    __shared__ ushort sB[2][PL][128 * 32];
    __shared__ int rowBase[BM];

    const int tid = threadIdx.x;
    const int m0 = blockIdx.x * BM;
    const int n0 = blockIdx.y * 128;

    if (GATHER) {
        for (int s = tid; s < BM; s += 256) {
            int r = m0 + s;
            int b = (r >= NV_PER_B) ? 1 : 0;
            int rp = r - b * NV_PER_B;
            int l, y, x;
            if (rp < 16384)      { l = 0; y = rp >> 7; x = rp & 127; }
            else if (rp < 20480) { int rr = rp - 16384; l = 1; y = rr >> 6; x = rr & 63; }
            else if (rp < 21504) { int rr = rp - 20480; l = 2; y = rr >> 5; x = rr & 31; }
            else                 { int rr = rp - 21504; l = 3; y = rr >> 4; x = rr & 15; }
            rowBase[s] = (((((b << 7) | y) << 7) | x) * 4 + l) << 8;
        }
        __syncthreads();
    }

    float4 pa[AIT], pb[4];

    // ---- global load of K-tile kt into regs ----
    auto loadA = [&](int kt) {
        #pragma unroll
        for (int i = 0; i < AIT; ++i) {
            int s = tid + i * 256;
            int r = s >> 3, c4 = s & 7;
            const float* src = GATHER
                ? A + rowBase[r] + kt * 32 + c4 * 4
                : A + (size_t)(m0 + r) * 256 + kt * 32 + c4 * 4;
            pa[i] = *(const float4*)src;
        }
        #pragma unroll
        for (int i = 0; i < 4; ++i) {
            int s = tid + i * 256;
            int r = s >> 3, c4 = s & 7;
            int bn = n0 + r;
            const float* src = ((bn < nsplit) ? B1 + (size_t)bn * 256
                                              : B2 + (size_t)(bn - nsplit) * 256)
                               + kt * 32 + c4 * 4;
            pb[i] = *(const float4*)src;
        }
    };

    // ---- convert + swizzled LDS write ----
    auto writeLDS = [&](int buf) {
        #pragma unroll
        for (int i = 0; i < AIT; ++i) {
            int s = tid + i * 256;
            int r = s >> 3, c4 = s & 7;
            float4 v = pa[i];
            ushort4 hi;
            hi.x = bf16_hi(v.x); hi.y = bf16_hi(v.y);
            hi.z = bf16_hi(v.z); hi.w = bf16_hi(v.w);
            int idx = r * 32 + ((((c4 >> 1) ^ (r & 3)) << 3) | ((c4 & 1) << 2));
            *(ushort4*)&sA[buf][0][idx] = hi;
            if (NPROD > 1) {
                ushort4 lo;
                lo.x = bf16_lo(v.x, hi.x); lo.y = bf16_lo(v.y, hi.y);
                lo.z = bf16_lo(v.z, hi.z); lo.w = bf16_lo(v.w, hi.w);
                *(ushort4*)&sA[buf][PL - 1][idx] = lo;
            }
        }
        #pragma unroll
        for (int i = 0; i < 4; ++i) {
            int s = tid + i * 256;
            int r = s >> 3, c4 = s & 7;
            float4 v = pb[i];
            ushort4 hi;
            hi.x = bf16_hi(v.x); hi.y = bf16_hi(v.y);
            hi.z = bf16_hi(v.z); hi.w = bf16_hi(v.w);
            int idx = r * 32 + ((((c4 >> 1) ^ (r & 3)) << 3) | ((c4 & 1) << 2));
            *(ushort4*)&sB[buf][0][idx] = hi;
            if (NPROD > 1) {
                ushort4 lo;
                lo.x = bf16_lo(v.x, hi.x); lo.y = bf16_lo(v.y, hi.y);
                lo.z = bf16_lo(v.z, hi.z); lo.w = bf16_lo(v.w, hi.w);
                *(ushort4*)&sB[buf][PL - 1][idx] = lo;
            }
        }
    };

    const int lane = tid & 63;
    const int wid  = tid >> 6;
    const int wrow = (wid >> 1) * (BM / 2);
    const int wcol = (wid & 1) * 64;
    const int fr   = lane & 15;
    const int ks   = lane >> 4;

    f32x4 acc[MI][4] = {};

    loadA(0);
    writeLDS(0);

    for (int kt = 0; kt < 8; ++kt) {
        __syncthreads();
        if (kt < 7) loadA(kt + 1);

        const int buf = kt & 1;
        bf16x8 ah[MI], al[MI], bh[4], bl[4];
        #pragma unroll
        for (int mi = 0; mi < MI; ++mi) {
            int row = wrow + mi * 16 + fr;
            int idx = row * 32 + ((ks ^ (row & 3)) << 3);
            ah[mi] = *(const bf16x8*)&sA[buf][0][idx];
            if (NPROD > 1) al[mi] = *(const bf16x8*)&sA[buf][PL - 1][idx];
        }
        #pragma unroll
        for (int ni = 0; ni < 4; ++ni) {
            int row = wcol + ni * 16 + fr;
            int idx = row * 32 + ((ks ^ (row & 3)) << 3);
            bh[ni] = *(const bf16x8*)&sB[buf][0][idx];
            if (NPROD > 1) bl[ni] = *(const bf16x8*)&sB[buf][PL - 1][idx];
        }
        #pragma unroll
        for (int mi = 0; mi < MI; ++mi)
            #pragma unroll
            for (int ni = 0; ni < 4; ++ni) {
                acc[mi][ni] = __builtin_amdgcn_mfma_f32_16x16x32_bf16(ah[mi], bh[ni], acc[mi][ni], 0, 0, 0);
                if (NPROD > 1) {
                    acc[mi][ni] = __builtin_amdgcn_mfma_f32_16x16x32_bf16(ah[mi], bl[ni], acc[mi][ni], 0, 0, 0);
                    acc[mi][ni] = __builtin_amdgcn_mfma_f32_16x16x32_bf16(al[mi], bh[ni], acc[mi][ni], 0, 0, 0);
                }
            }

        if (kt < 7) writeLDS((kt + 1) & 1);
    }

    // epilogue: D[row=(lane>>4)*4+r][col=lane&15] per 16x16 frag
    #pragma unroll
    for (int mi = 0; mi < MI; ++mi)
        #pragma unroll
        for (int ni = 0; ni < 4; ++ni) {
            int col = n0 + wcol + ni * 16 + fr;
            float bs = (col < nsplit) ? bias1[col] : bias2[col - nsplit];
            int rbase = m0 + wrow + mi * 16 + ks * 4;
            #pragma unroll
            for (int rr = 0; rr < 4; ++rr) {
                float val = acc[mi][ni][rr] + bs;
                if (OUTBF16)
                    ((ushort*)Out)[(size_t)(rbase + rr) * ldo + col] = bf16_rne(val);
                else
                    ((float*)Out)[(size_t)(rbase + rr) * ldo + col] = val;
            }
        }
}

// ---------------------------------------------------------------------------
// Sampling: 4 queries per block, 256 threads, bf16 vproj gathers (8B loads).
// ---------------------------------------------------------------------------
__global__ __launch_bounds__(256)
void sample4(const ushort* __restrict__ vproj,  // [MROWS][256] bf16
             const float* __restrict__ qbuf,    // [Q][384]: 256 offs | 128 aw logits
             const float* __restrict__ ref,     // [Q][2]
             float* __restrict__ mid)           // [Q][256]
{
    __shared__ int   s_row[4][128][4];
    __shared__ float s_w[4][128][4];
    __shared__ float s_logit[4][16][8];
    __shared__ float s_aw[4][16][8];

    const int tid = threadIdx.x;
    const int q0 = blockIdx.x * 4;

    #pragma unroll
    for (int it = 0; it < 2; ++it) {
        const int cc = tid + it * 256;
        const int qq = cc >> 7, c = cc & 127;
        const int q = q0 + qq;
        const int b = (q >= QPERB) ? 1 : 0;
        const int lp = c >> 3, l = lp >> 2;
        const float offx = qbuf[(size_t)q * 384 + c * 2 + 0];
        const float offy = qbuf[(size_t)q * 384 + c * 2 + 1];
        float rx = fminf(fmaxf(ref[q * 2 + 0], 0.f), 1.f);
        float ry = fminf(fmaxf(ref[q * 2 + 1], 0.f), 1.f);
        const float eps = 1e-5f;
        const float isx = logf(fmaxf(rx, eps) / fmaxf(1.f - rx, eps));
        const float isy = logf(fmaxf(ry, eps) / fmaxf(1.f - ry, eps));
        const float locx = 1.f / (1.f + expf(-(isx + offx)));
        const float locy = 1.f / (1.f + expf(-(isy + offy)));
        const int Wl = HMAX >> l, Hl = HMAX >> l;
        const float x = locx * (float)Wl - 0.5f;
        const float y = locy * (float)Hl - 0.5f;
        const float x0f = floorf(x), y0f = floorf(y);
        const float wx1 = x - x0f, wx0 = 1.f - wx1;
        const float wy1 = y - y0f, wy0 = 1.f - wy1;
        const int x0 = (int)x0f, y0 = (int)y0f;
        const int lo = (l == 0) ? 0 : (l == 1) ? 16384 : (l == 2) ? 20480 : 21504;
        const int base = b * NV_PER_B + lo;
        const int   xs[2] = {x0, x0 + 1};
        const int   ys[2] = {y0, y0 + 1};
        const float wxs[2] = {wx0, wx1};
        const float wys[2] = {wy0, wy1};
        #pragma unroll
        for (int cy = 0; cy < 2; ++cy)
            #pragma unroll
            for (int cx = 0; cx < 2; ++cx) {
                const int xi = xs[cx], yi = ys[cy];
                const bool valid = (xi >= 0) & (xi < Wl) & (yi >= 0) & (yi < Hl);
                const int idx = cy * 2 + cx;
                s_row[qq][c][idx] = valid ? (base + yi * Wl + xi) : 0;
                s_w[qq][c][idx]   = valid ? (wys[cy] * wxs[cx]) : 0.f;
            }
        s_logit[qq][lp][c & 7] = qbuf[(size_t)q * 384 + 256 + c];
    }
    __syncthreads();

    if (tid < 32) {
        const int qq = tid >> 3, h = tid & 7;
        float m = -INFINITY;
        #pragma unroll
        for (int j = 0; j < 16; ++j) m = fmaxf(m, s_logit[qq][j][h]);
        float s = 0.f;
        #pragma unroll
        for (int j = 0; j < 16; ++j) s += expf(s_logit[qq][j][h] - m);
        const float inv = 1.f / s;
        #pragma unroll
        for (int j = 0; j < 16; ++j)
            s_aw[qq][j][h] = expf(s_logit[qq][j][h] - m) * inv;
    }
    __syncthreads();

    const int qq = tid >> 6, t6 = tid & 63;
    const int h = t6 >> 3, d4 = t6 & 7;
    const int q = q0 + qq;
    float ax = 0.f, ay = 0.f, az = 0.f, aw_ = 0.f;
    #pragma unroll
    for (int lp = 0; lp < 16; ++lp) {
        const int c = lp * 8 + h;
        const float aw = s_aw[qq][lp][h];
        float sx = 0.f, sy = 0.f, sz = 0.f, sw = 0.f;
        #pragma unroll
        for (int j = 0; j < 4; ++j) {
            const int row = s_row[qq][c][j];
            const float w = s_w[qq][c][j];
            const uint2 u = *(const uint2*)&vproj[(size_t)row * 256 + h * 32 + d4 * 4];
            const float v0 = __builtin_bit_cast(float, u.x << 16);
            const float v1 = __builtin_bit_cast(float, u.x & 0xFFFF0000u);
            const float v2 = __builtin_bit_cast(float, u.y << 16);
            const float v3 = __builtin_bit_cast(float, u.y & 0xFFFF0000u);
            sx = fmaf(w, v0, sx); sy = fmaf(w, v1, sy);
            sz = fmaf(w, v2, sz); sw = fmaf(w, v3, sw);
        }
        ax = fmaf(aw, sx, ax); ay = fmaf(aw, sy, ay);
        az = fmaf(aw, sz, az); aw_ = fmaf(aw, sw, aw_);
    }
    float4 o = {ax, ay, az, aw_};
    *(float4*)&mid[(size_t)q * 256 + t6 * 4] = o;
}

// ---------------------------------------------------------------------------
extern "C" void kernel_launch(void* const* d_in, const int* in_sizes, int n_in,
                              void* d_out, int out_size, void* d_ws, size_t ws_size,
                              hipStream_t stream)
{
    const float* query  = (const float*)d_in[0];
    const float* ref    = (const float*)d_in[1];
    const float* values = (const float*)d_in[2];
    const float* W_so   = (const float*)d_in[3];
    const float* b_so   = (const float*)d_in[4];
    const float* W_aw   = (const float*)d_in[5];
    const float* b_aw   = (const float*)d_in[6];
    const float* W_v    = (const float*)d_in[7];
    const float* b_v    = (const float*)d_in[8];
    const float* W_o    = (const float*)d_in[9];
    const float* b_o    = (const float*)d_in[10];
    float* out = (float*)d_out;

    ushort* vproj = (ushort*)d_ws;                     // [43520][256] bf16
    float* qbuf  = (float*)d_ws + ((size_t)MROWS * 256 * 2 + 3) / 4;  // [8192][384] f32
    float* mid   = qbuf + (size_t)QTOT * 384;          // [8192][256] f32

    dim3 blk(256);
    // 1) compact value projection: vproj = bf16(values_valid @ W_v^T + b_v)
    gemm_split<1, 128, 1, 1><<<dim3(MROWS / 128, 2), blk, 0, stream>>>(
        values, W_v, W_v, b_v, b_v, vproj, 256, 256);
    // 2) query projections (full split — position-sensitive)
    gemm_split<0, 64, 3, 0><<<dim3(QTOT / 64, 3), blk, 0, stream>>>(
        query, W_so, W_aw, b_so, b_aw, qbuf, 256, 384);
    // 3) deformable sampling + softmax-weighted head accumulation
    sample4<<<dim3(QTOT / 4), blk, 0, stream>>>(vproj, qbuf, ref, mid);
    // 4) output projection (plain bf16 — error-tolerant)
    gemm_split<0, 64, 1, 0><<<dim3(QTOT / 64, 2), blk, 0, stream>>>(
        mid, W_o, W_o, b_o, b_o, out, 256, 256);
}

// Round 8
// 262.953 us; speedup vs baseline: 1.4418x; 1.0353x over previous
//
#include <hip/hip_runtime.h>
#include <math.h>

// Problem constants (fixed by setup_inputs)
#define QTOT   8192
#define LNUM   4
#define PNUM   4
#define NHEAD  8
#define DHEAD  32
#define HMAX   128
#define NV_PER_B 21760           // 128^2 + 64^2 + 32^2 + 16^2
#define MROWS  (2 * NV_PER_B)    // 43520 valid value rows
#define QPERB  4096              // batch_offsets = [0, 4096]

// grouped-GEMM grid split
#define G1_MT  (MROWS / 128)     // 340 m-tiles for vproj GEMM
#define G1_BLKS (G1_MT * 2)      // 680 (N=256 -> 2 n-tiles)
#define G2_BLKS (128 * 3)        // 384 (M=8192/64, N=384 -> 3 n-tiles)

typedef __attribute__((ext_vector_type(8))) short bf16x8;
typedef __attribute__((ext_vector_type(4))) float f32x4;

static __device__ __forceinline__ ushort bf16_hi(float f) {
    return (ushort)(__builtin_bit_cast(unsigned int, f) >> 16);
}
static __device__ __forceinline__ ushort bf16_lo(float f, ushort hi) {
    float hf = __builtin_bit_cast(float, ((unsigned int)hi) << 16);
    return (ushort)(__builtin_bit_cast(unsigned int, f - hf) >> 16);
}
static __device__ __forceinline__ ushort bf16_rne(float f) {
    unsigned u = __builtin_bit_cast(unsigned int, f);
    unsigned rr = (u + 0x7FFFu + ((u >> 16) & 1u)) >> 16;
    return (ushort)rr;
}

// ---------------------------------------------------------------------------
// Split-bf16 MFMA NT GEMM body: Out[M][ldo] = A[M][256] * B[N][256]^T + bias
// NPROD=3: a*b ~= ahi*bhi + ahi*blo + alo*bhi; NPROD=1: plain bf16.
// OUTBF16: store bf16 (RNE). GATHER: A rows from sparse values tensor.
// BMx128 tile, BK=32, 256 threads = 4 waves (2x2), 16x16x32 MFMA,
// double-buffered LDS with XOR chunk-swizzle. smem is caller-provided.
// LDS bytes needed: (2*PL*BM*32 + 2*PL*128*32)*2 + (GATHER ? 4*BM : 0)
//   mode1 <1,128,1,1>: 16K + 16K + 512 = 32.5 KB
//   mode2 <0, 64,3,0>: 16K + 32K       = 48 KB   <-- max
//   out   <0, 64,1,0>:  8K + 16K       = 24 KB
// ---------------------------------------------------------------------------
template<int GATHER, int BM, int NPROD, int OUTBF16>
__device__ __forceinline__
void gemm_body(const float* __restrict__ A,
               const float* __restrict__ B1,
               const float* __restrict__ B2,
               const float* __restrict__ bias1,
               const float* __restrict__ bias2,
               void* __restrict__ Out,
               int nsplit, int ldo, int bx, int by, char* smem)
{
    constexpr int MI  = BM / 32;          // m-frags per wave
    constexpr int AIT = BM * 8 / 256;     // float4 staging slots per thread (A)
    constexpr int PL  = (NPROD > 1) ? 2 : 1;   // LDS planes (hi[,lo])
    ushort* sAp = (ushort*)smem;                    // [2][PL][BM*32]
    ushort* sBp = sAp + 2 * PL * BM * 32;           // [2][PL][128*32]
    int* rowBase = (int*)(sBp + 2 * PL * 128 * 32); // [BM] (GATHER only)

    const int tid = threadIdx.x;
    const int m0 = bx * BM;
    const int n0 = by * 128;

    if (GATHER) {
        for (int s = tid; s < BM; s += 256) {
            int r = m0 + s;
            int b = (r >= NV_PER_B) ? 1 : 0;
            int rp = r - b * NV_PER_B;
            int l, y, x;
            if (rp < 16384)      { l = 0; y = rp >> 7; x = rp & 127; }
            else if (rp < 20480) { int rr = rp - 16384; l = 1; y = rr >> 6; x = rr & 63; }
            else if (rp < 21504) { int rr = rp - 20480; l = 2; y = rr >> 5; x = rr & 31; }
            else                 { int rr = rp - 21504; l = 3; y = rr >> 4; x = rr & 15; }
            rowBase[s] = (((((b << 7) | y) << 7) | x) * 4 + l) << 8;
        }
        __syncthreads();
    }

    float4 pa[AIT], pb[4];

    auto loadA = [&](int kt) {
        #pragma unroll
        for (int i = 0; i < AIT; ++i) {
            int s = tid + i * 256;
            int r = s >> 3, c4 = s & 7;
            const float* src = GATHER
                ? A + rowBase[r] + kt * 32 + c4 * 4
                : A + (size_t)(m0 + r) * 256 + kt * 32 + c4 * 4;
            pa[i] = *(const float4*)src;
        }
        #pragma unroll
        for (int i = 0; i < 4; ++i) {
            int s = tid + i * 256;
            int r = s >> 3, c4 = s & 7;
            int bn = n0 + r;
            const float* src = ((bn < nsplit) ? B1 + (size_t)bn * 256
                                              : B2 + (size_t)(bn - nsplit) * 256)
                               + kt * 32 + c4 * 4;
            pb[i] = *(const float4*)src;
        }
    };

    auto writeLDS = [&](int buf) {
        #pragma unroll
        for (int i = 0; i < AIT; ++i) {
            int s = tid + i * 256;
            int r = s >> 3, c4 = s & 7;
            float4 v = pa[i];
            ushort4 hi;
            hi.x = bf16_hi(v.x); hi.y = bf16_hi(v.y);
            hi.z = bf16_hi(v.z); hi.w = bf16_hi(v.w);
            int idx = r * 32 + ((((c4 >> 1) ^ (r & 3)) << 3) | ((c4 & 1) << 2));
            *(ushort4*)&sAp[(buf * PL + 0) * BM * 32 + idx] = hi;
            if (NPROD > 1) {
                ushort4 lo;
                lo.x = bf16_lo(v.x, hi.x); lo.y = bf16_lo(v.y, hi.y);
                lo.z = bf16_lo(v.z, hi.z); lo.w = bf16_lo(v.w, hi.w);
                *(ushort4*)&sAp[(buf * PL + PL - 1) * BM * 32 + idx] = lo;
            }
        }
        #pragma unroll
        for (int i = 0; i < 4; ++i) {
            int s = tid + i * 256;
            int r = s >> 3, c4 = s & 7;
            float4 v = pb[i];
            ushort4 hi;
            hi.x = bf16_hi(v.x); hi.y = bf16_hi(v.y);
            hi.z = bf16_hi(v.z); hi.w = bf16_hi(v.w);
            int idx = r * 32 + ((((c4 >> 1) ^ (r & 3)) << 3) | ((c4 & 1) << 2));
            *(ushort4*)&sBp[(buf * PL + 0) * 128 * 32 + idx] = hi;
            if (NPROD > 1) {
                ushort4 lo;
                lo.x = bf16_lo(v.x, hi.x); lo.y = bf16_lo(v.y, hi.y);
                lo.z = bf16_lo(v.z, hi.z); lo.w = bf16_lo(v.w, hi.w);
                *(ushort4*)&sBp[(buf * PL + PL - 1) * 128 * 32 + idx] = lo;
            }
        }
    };

    const int lane = tid & 63;
    const int wid  = tid >> 6;
    const int wrow = (wid >> 1) * (BM / 2);
    const int wcol = (wid & 1) * 64;
    const int fr   = lane & 15;
    const int ks   = lane >> 4;

    f32x4 acc[MI][4] = {};

    loadA(0);
    writeLDS(0);

    for (int kt = 0; kt < 8; ++kt) {
        __syncthreads();
        if (kt < 7) loadA(kt + 1);

        const int buf = kt & 1;
        bf16x8 ah[MI], al[MI], bh[4], bl[4];
        #pragma unroll
        for (int mi = 0; mi < MI; ++mi) {
            int row = wrow + mi * 16 + fr;
            int idx = row * 32 + ((ks ^ (row & 3)) << 3);
            ah[mi] = *(const bf16x8*)&sAp[(buf * PL + 0) * BM * 32 + idx];
            if (NPROD > 1) al[mi] = *(const bf16x8*)&sAp[(buf * PL + PL - 1) * BM * 32 + idx];
        }
        #pragma unroll
        for (int ni = 0; ni < 4; ++ni) {
            int row = wcol + ni * 16 + fr;
            int idx = row * 32 + ((ks ^ (row & 3)) << 3);
            bh[ni] = *(const bf16x8*)&sBp[(buf * PL + 0) * 128 * 32 + idx];
            if (NPROD > 1) bl[ni] = *(const bf16x8*)&sBp[(buf * PL + PL - 1) * 128 * 32 + idx];
        }
        #pragma unroll
        for (int mi = 0; mi < MI; ++mi)
            #pragma unroll
            for (int ni = 0; ni < 4; ++ni) {
                acc[mi][ni] = __builtin_amdgcn_mfma_f32_16x16x32_bf16(ah[mi], bh[ni], acc[mi][ni], 0, 0, 0);
                if (NPROD > 1) {
                    acc[mi][ni] = __builtin_amdgcn_mfma_f32_16x16x32_bf16(ah[mi], bl[ni], acc[mi][ni], 0, 0, 0);
                    acc[mi][ni] = __builtin_amdgcn_mfma_f32_16x16x32_bf16(al[mi], bh[ni], acc[mi][ni], 0, 0, 0);
                }
            }

        if (kt < 7) writeLDS((kt + 1) & 1);
    }

    // epilogue: D[row=(lane>>4)*4+r][col=lane&15] per 16x16 frag
    #pragma unroll
    for (int mi = 0; mi < MI; ++mi)
        #pragma unroll
        for (int ni = 0; ni < 4; ++ni) {
            int col = n0 + wcol + ni * 16 + fr;
            float bs = (col < nsplit) ? bias1[col] : bias2[col - nsplit];
            int rbase = m0 + wrow + mi * 16 + ks * 4;
            #pragma unroll
            for (int rr = 0; rr < 4; ++rr) {
                float val = acc[mi][ni][rr] + bs;
                if (OUTBF16)
                    ((ushort*)Out)[(size_t)(rbase + rr) * ldo + col] = bf16_rne(val);
                else
                    ((float*)Out)[(size_t)(rbase + rr) * ldo + col] = val;
            }
        }
}

// ---------------------------------------------------------------------------
// Grouped launch: GEMM1 (vproj) and GEMM2 (qbuf) are independent — run them
// as one grid so their work fills the machine concurrently.
// blocks [0, 680): mode 1 — vproj = bf16(values_valid @ W_v^T + b_v)
// blocks [680, 1064): mode 2 — qbuf = query @ [W_so;W_aw]^T + bias (3-prod)
// ---------------------------------------------------------------------------
__global__ __launch_bounds__(256)
void fused_g12(const float* __restrict__ values,
               const float* __restrict__ W_v,  const float* __restrict__ b_v,
               const float* __restrict__ query,
               const float* __restrict__ W_so, const float* __restrict__ W_aw,
               const float* __restrict__ b_so, const float* __restrict__ b_aw,
               ushort* __restrict__ vproj, float* __restrict__ qbuf)
{
    extern __shared__ char smem[];
    const int f = blockIdx.x;
    if (f < G1_BLKS) {
        gemm_body<1, 128, 1, 1>(values, W_v, W_v, b_v, b_v, vproj,
                                256, 256, f % G1_MT, f / G1_MT, smem);
    } else {
        const int g = f - G1_BLKS;
        gemm_body<0, 64, 3, 0>(query, W_so, W_aw, b_so, b_aw, qbuf,
                               256, 384, g % 128, g / 128, smem);
    }
}

// output projection kernel (separate: depends on sample4's mid)
__global__ __launch_bounds__(256)
void gemm_o(const float* __restrict__ mid,
            const float* __restrict__ W_o, const float* __restrict__ b_o,
            float* __restrict__ out)
{
    extern __shared__ char smem[];
    gemm_body<0, 64, 1, 0>(mid, W_o, W_o, b_o, b_o, out,
                           256, 256, blockIdx.x, blockIdx.y, smem);
}

// ---------------------------------------------------------------------------
// Sampling: 4 queries per block, 256 threads, bf16 vproj gathers (8B loads).
// ---------------------------------------------------------------------------
__global__ __launch_bounds__(256)
void sample4(const ushort* __restrict__ vproj,  // [MROWS][256] bf16
             const float* __restrict__ qbuf,    // [Q][384]: 256 offs | 128 aw logits
             const float* __restrict__ ref,     // [Q][2]
             float* __restrict__ mid)           // [Q][256]
{
    __shared__ int   s_row[4][128][4];
    __shared__ float s_w[4][128][4];
    __shared__ float s_logit[4][16][8];
    __shared__ float s_aw[4][16][8];

    const int tid = threadIdx.x;
    const int q0 = blockIdx.x * 4;

    #pragma unroll
    for (int it = 0; it < 2; ++it) {
        const int cc = tid + it * 256;
        const int qq = cc >> 7, c = cc & 127;
        const int q = q0 + qq;
        const int b = (q >= QPERB) ? 1 : 0;
        const int lp = c >> 3, l = lp >> 2;
        const float offx = qbuf[(size_t)q * 384 + c * 2 + 0];
        const float offy = qbuf[(size_t)q * 384 + c * 2 + 1];
        float rx = fminf(fmaxf(ref[q * 2 + 0], 0.f), 1.f);
        float ry = fminf(fmaxf(ref[q * 2 + 1], 0.f), 1.f);
        const float eps = 1e-5f;
        const float isx = logf(fmaxf(rx, eps) / fmaxf(1.f - rx, eps));
        const float isy = logf(fmaxf(ry, eps) / fmaxf(1.f - ry, eps));
        const float locx = 1.f / (1.f + expf(-(isx + offx)));
        const float locy = 1.f / (1.f + expf(-(isy + offy)));
        const int Wl = HMAX >> l, Hl = HMAX >> l;
        const float x = locx * (float)Wl - 0.5f;
        const float y = locy * (float)Hl - 0.5f;
        const float x0f = floorf(x), y0f = floorf(y);
        const float wx1 = x - x0f, wx0 = 1.f - wx1;
        const float wy1 = y - y0f, wy0 = 1.f - wy1;
        const int x0 = (int)x0f, y0 = (int)y0f;
        const int lo = (l == 0) ? 0 : (l == 1) ? 16384 : (l == 2) ? 20480 : 21504;
        const int base = b * NV_PER_B + lo;
        const int   xs[2] = {x0, x0 + 1};
        const int   ys[2] = {y0, y0 + 1};
        const float wxs[2] = {wx0, wx1};
        const float wys[2] = {wy0, wy1};
        #pragma unroll
        for (int cy = 0; cy < 2; ++cy)
            #pragma unroll
            for (int cx = 0; cx < 2; ++cx) {
                const int xi = xs[cx], yi = ys[cy];
                const bool valid = (xi >= 0) & (xi < Wl) & (yi >= 0) & (yi < Hl);
                const int idx = cy * 2 + cx;
                s_row[qq][c][idx] = valid ? (base + yi * Wl + xi) : 0;
                s_w[qq][c][idx]   = valid ? (wys[cy] * wxs[cx]) : 0.f;
            }
        s_logit[qq][lp][c & 7] = qbuf[(size_t)q * 384 + 256 + c];
    }
    __syncthreads();

    if (tid < 32) {
        const int qq = tid >> 3, h = tid & 7;
        float m = -INFINITY;
        #pragma unroll
        for (int j = 0; j < 16; ++j) m = fmaxf(m, s_logit[qq][j][h]);
        float s = 0.f;
        #pragma unroll
        for (int j = 0; j < 16; ++j) s += expf(s_logit[qq][j][h] - m);
        const float inv = 1.f / s;
        #pragma unroll
        for (int j = 0; j < 16; ++j)
            s_aw[qq][j][h] = expf(s_logit[qq][j][h] - m) * inv;
    }
    __syncthreads();

    const int qq = tid >> 6, t6 = tid & 63;
    const int h = t6 >> 3, d4 = t6 & 7;
    const int q = q0 + qq;
    float ax = 0.f, ay = 0.f, az = 0.f, aw_ = 0.f;
    #pragma unroll
    for (int lp = 0; lp < 16; ++lp) {
        const int c = lp * 8 + h;
        const float aw = s_aw[qq][lp][h];
        float sx = 0.f, sy = 0.f, sz = 0.f, sw = 0.f;
        #pragma unroll
        for (int j = 0; j < 4; ++j) {
            const int row = s_row[qq][c][j];
            const float w = s_w[qq][c][j];
            const uint2 u = *(const uint2*)&vproj[(size_t)row * 256 + h * 32 + d4 * 4];
            const float v0 = __builtin_bit_cast(float, u.x << 16);
            const float v1 = __builtin_bit_cast(float, u.x & 0xFFFF0000u);
            const float v2 = __builtin_bit_cast(float, u.y << 16);
            const float v3 = __builtin_bit_cast(float, u.y & 0xFFFF0000u);
            sx = fmaf(w, v0, sx); sy = fmaf(w, v1, sy);
            sz = fmaf(w, v2, sz); sw = fmaf(w, v3, sw);
        }
        ax = fmaf(aw, sx, ax); ay = fmaf(aw, sy, ay);
        az = fmaf(aw, sz, az); aw_ = fmaf(aw, sw, aw_);
    }
    float4 o = {ax, ay, az, aw_};
    *(float4*)&mid[(size_t)q * 256 + t6 * 4] = o;
}

// ---------------------------------------------------------------------------
extern "C" void kernel_launch(void* const* d_in, const int* in_sizes, int n_in,
                              void* d_out, int out_size, void* d_ws, size_t ws_size,
                              hipStream_t stream)
{
    const float* query  = (const float*)d_in[0];
    const float* ref    = (const float*)d_in[1];
    const float* values = (const float*)d_in[2];
    const float* W_so   = (const float*)d_in[3];
    const float* b_so   = (const float*)d_in[4];
    const float* W_aw   = (const float*)d_in[5];
    const float* b_aw   = (const float*)d_in[6];
    const float* W_v    = (const float*)d_in[7];
    const float* b_v    = (const float*)d_in[8];
    const float* W_o    = (const float*)d_in[9];
    const float* b_o    = (const float*)d_in[10];
    float* out = (float*)d_out;

    ushort* vproj = (ushort*)d_ws;                     // [43520][256] bf16
    float* qbuf  = (float*)d_ws + ((size_t)MROWS * 256 * 2) / 4;  // [8192][384] f32
    float* mid   = qbuf + (size_t)QTOT * 384;          // [8192][256] f32

    // mode-2 needs 48 KB (sA 16K + sB 32K); +1 KB pad for rowBase (mode 1).
    // R7 BUG: was 33 KB -> mode-2 LDS overflow. Fixed.
    const int smem_bytes = 48 * 1024 + 1024;

    dim3 blk(256);
    // 1+2) grouped: vproj GEMM (680 blocks) ++ query projections (384 blocks)
    fused_g12<<<dim3(G1_BLKS + G2_BLKS), blk, smem_bytes, stream>>>(
        values, W_v, b_v, query, W_so, W_aw, b_so, b_aw, vproj, qbuf);
    // 3) deformable sampling + softmax-weighted head accumulation
    sample4<<<dim3(QTOT / 4), blk, 0, stream>>>(vproj, qbuf, ref, mid);
    // 4) output projection
    gemm_o<<<dim3(QTOT / 64, 2), blk, smem_bytes, stream>>>(mid, W_o, b_o, out);
}